// Round 1
// baseline (301.985 us; speedup 1.0000x reference)
//
#include <hip/hip_runtime.h>

#define U_ROWS 20000
#define I_COLS 10000
#define LDI    10001
#define B_N    4096
#define SU     313   // ceil(10000/32) K-steps for u-gemm
#define SC     625   // 20000/32 K-steps for c-gemm

typedef __attribute__((ext_vector_type(8))) __bf16 bf16x8;
typedef __attribute__((ext_vector_type(4))) float f32x4;

__device__ __forceinline__ unsigned short f2bf(float f) {
    unsigned int u = __float_as_uint(f);
    return (unsigned short)((u + 0x7FFFu + ((u >> 16) & 1u)) >> 16);  // RTN-even
}

// Pack W [64][n_k] fp32 -> bf16 in MFMA B-fragment order:
// out[((s*4+nb)*64 + l)*8 + j] = bf16(W[nb*16 + (l&15)][s*32 + (l>>4)*8 + j]), 0 beyond n_k
__global__ __launch_bounds__(256) void k_pack_w(const float* __restrict__ W,
                                                unsigned short* __restrict__ out,
                                                int n_k, int n_steps)
{
    int idx = blockIdx.x * blockDim.x + threadIdx.x;
    if (idx >= n_steps * 2048) return;
    int j  = idx & 7;
    int l  = (idx >> 3) & 63;
    int nb = (idx >> 9) & 3;
    int s  = idx >> 11;
    int n  = nb * 16 + (l & 15);
    int k  = s * 32 + ((l >> 4) << 3) + j;
    float v = (k < n_k) ? W[(size_t)n * n_k + k] : 0.0f;
    out[idx] = f2bf(v);
}

// transpose in[rows][cols] -> out[cols][rows] (fp32, tiny MLP weights)
__global__ __launch_bounds__(256) void k_tr(const float* __restrict__ in,
                                            float* __restrict__ out, int rows, int cols)
{
    int idx = blockIdx.x * blockDim.x + threadIdx.x;
    if (idx >= rows * cols) return;
    int r = idx / cols, c = idx % cols;
    out[c * rows + r] = in[idx];
}

// u_emb partial GEMM: Upart[p][r][n] = sum over i-range of A[u_r, i] * W_u[n, i]
// block: 64 batch rows (4 waves x 16), K-step 32, LDS tile At[64][32] rotate-swizzled
__global__ __launch_bounds__(256) void k_gemm_u(
    const float* __restrict__ A, const int* __restrict__ uidx,
    const unsigned short* __restrict__ Bp, float* __restrict__ Upart,
    int steps_per)
{
    __shared__ float At[64 * 32];
    const int t = threadIdx.x, lane = t & 63, w = t >> 6;
    const int mb = blockIdx.x & 63, p = blockIdx.x >> 6;
    const int r0 = mb * 64;
    const int s0 = p * steps_per;
    const int s1 = (SU < s0 + steps_per) ? SU : (s0 + steps_per);
    const int rl = lane & 15, g = lane >> 4;

    f32x4 acc[4];
#pragma unroll
    for (int nb = 0; nb < 4; ++nb) acc[nb] = (f32x4)(0.0f);

    int urow[8];
#pragma unroll
    for (int q = 0; q < 8; ++q) urow[q] = uidx[r0 + q * 8 + (t >> 5)];

    for (int s = s0; s < s1; ++s) {
        const int k0 = s * 32;
        float sv[8];
#pragma unroll
        for (int q = 0; q < 8; ++q) {
            int row = q * 8 + (t >> 5);
            int col = k0 + (((t & 31) + row) & 31);   // rotate swizzle by row
            sv[q] = (col < I_COLS) ? A[(size_t)urow[q] * LDI + col] : 0.0f;
        }
        __syncthreads();  // prev iteration's LDS reads done before overwrite
#pragma unroll
        for (int q = 0; q < 8; ++q) {
            int row = q * 8 + (t >> 5);
            At[row * 32 + (t & 31)] = sv[q];
        }
        __syncthreads();

        bf16x8 bv[4];
#pragma unroll
        for (int nb = 0; nb < 4; ++nb)
            bv[nb] = *(const bf16x8*)(Bp + ((size_t)(s * 4 + nb) * 64 + lane) * 8);

        const int r_loc = w * 16 + rl;
        unsigned int au[8];
#pragma unroll
        for (int j = 0; j < 8; ++j) {
            int c = g * 8 + j;
            au[j] = __float_as_uint(At[r_loc * 32 + ((c - r_loc) & 31)]);
        }
        union { int i[4]; bf16x8 v; } af;
#pragma unroll
        for (int q = 0; q < 4; ++q)
            af.i[q] = __builtin_amdgcn_perm(au[2 * q + 1], au[2 * q], 0x07060302);
#pragma unroll
        for (int nb = 0; nb < 4; ++nb)
            acc[nb] = __builtin_amdgcn_mfma_f32_16x16x32_bf16(af.v, bv[nb], acc[nb], 0, 0, 0);
    }

    float* outp = Upart + (size_t)p * B_N * 64;
#pragma unroll
    for (int nb = 0; nb < 4; ++nb)
#pragma unroll
        for (int reg = 0; reg < 4; ++reg) {
            int r = r0 + w * 16 + g * 4 + reg;
            outp[(size_t)r * 64 + nb * 16 + rl] = acc[nb][reg];
        }
}

// Ct partial GEMM: Cpart[p][i][n] = sum over u-range of A[u, i] * W_i[n, u]
// block: 64 i-columns (4 waves x 16), K-step 32 u-rows, LDS tile At[32][64] rotate-swizzled
__global__ __launch_bounds__(256) void k_gemm_c(
    const float* __restrict__ A, const unsigned short* __restrict__ Bp,
    float* __restrict__ Cpart, int n_mb, int steps_per)
{
    __shared__ float At[32 * 64];
    const int t = threadIdx.x, lane = t & 63, w = t >> 6;
    const int mb = blockIdx.x % n_mb, p = blockIdx.x / n_mb;
    const int i0 = mb * 64;
    const int s0 = p * steps_per;
    const int s1 = (SC < s0 + steps_per) ? SC : (s0 + steps_per);
    const int rl = lane & 15, g = lane >> 4;

    f32x4 acc[4];
#pragma unroll
    for (int nb = 0; nb < 4; ++nb) acc[nb] = (f32x4)(0.0f);

    for (int s = s0; s < s1; ++s) {
        const int u0 = s * 32;
        float sv[8];
#pragma unroll
        for (int q = 0; q < 8; ++q) {
            int ul = q * 4 + w;
            int col = i0 + ((lane + ul) & 63);        // rotate swizzle by row
            sv[q] = (col < I_COLS) ? A[(size_t)(u0 + ul) * LDI + col] : 0.0f;
        }
        __syncthreads();
#pragma unroll
        for (int q = 0; q < 8; ++q) At[(q * 4 + w) * 64 + lane] = sv[q];
        __syncthreads();

        bf16x8 bv[4];
#pragma unroll
        for (int nb = 0; nb < 4; ++nb)
            bv[nb] = *(const bf16x8*)(Bp + ((size_t)(s * 4 + nb) * 64 + lane) * 8);

        const int i_loc = w * 16 + rl;
        unsigned int au[8];
#pragma unroll
        for (int j = 0; j < 8; ++j) {
            int ul = g * 8 + j;
            au[j] = __float_as_uint(At[ul * 64 + ((i_loc - ul) & 63)]);
        }
        union { int i[4]; bf16x8 v; } af;
#pragma unroll
        for (int q = 0; q < 4; ++q)
            af.i[q] = __builtin_amdgcn_perm(au[2 * q + 1], au[2 * q], 0x07060302);
#pragma unroll
        for (int nb = 0; nb < 4; ++nb)
            acc[nb] = __builtin_amdgcn_mfma_f32_16x16x32_bf16(af.v, bv[nb], acc[nb], 0, 0, 0);
    }

    float* outp = Cpart + (size_t)p * I_COLS * 64;
#pragma unroll
    for (int nb = 0; nb < 4; ++nb)
#pragma unroll
        for (int reg = 0; reg < 4; ++reg) {
            int i = i0 + w * 16 + g * 4 + reg;
            if (i < I_COLS) outp[(size_t)i * 64 + nb * 16 + rl] = acc[nb][reg];
        }
}

__device__ __forceinline__ float redsum64(float x) {
    x += __shfl_xor(x, 1);  x += __shfl_xor(x, 2);  x += __shfl_xor(x, 4);
    x += __shfl_xor(x, 8);  x += __shfl_xor(x, 16); x += __shfl_xor(x, 32);
    return x;
}
__device__ __forceinline__ float redsum32(float x) {
    x += __shfl_xor(x, 1); x += __shfl_xor(x, 2); x += __shfl_xor(x, 4);
    x += __shfl_xor(x, 8); x += __shfl_xor(x, 16);
    return x;
}
__device__ __forceinline__ float redsum16(float x) {
    x += __shfl_xor(x, 1); x += __shfl_xor(x, 2); x += __shfl_xor(x, 4);
    x += __shfl_xor(x, 8);
    return x;
}

// one wave per batch row: reduce partials, mask corrections, full MLP
__global__ __launch_bounds__(256) void k_epi(
    const float* __restrict__ A, const int* __restrict__ uidx, const int* __restrict__ iidx,
    const float* __restrict__ Upart, const float* __restrict__ Cpart, int NP, int NC,
    const float* __restrict__ Wu, const float* __restrict__ Wi,
    const float* __restrict__ Wt1, const float* __restrict__ b1, const float* __restrict__ g1, const float* __restrict__ be1,
    const float* __restrict__ Wt2, const float* __restrict__ b2, const float* __restrict__ g2, const float* __restrict__ be2,
    const float* __restrict__ Wt3, const float* __restrict__ b3, const float* __restrict__ g3, const float* __restrict__ be3,
    const float* __restrict__ Wp, const float* __restrict__ bp,
    float* __restrict__ out)
{
    const int t = threadIdx.x, lane = t & 63, w = t >> 6;
    const int r = blockIdx.x * 4 + w;
    const int u = uidx[r], it = iidx[r];
    const float a_ui = A[(size_t)u * LDI + it];

    float ue = 0.f, ie = 0.f;
    for (int p0 = 0; p0 < NP; ++p0) ue += Upart[((size_t)p0 * B_N + r) * 64 + lane];
    for (int p0 = 0; p0 < NC; ++p0) ie += Cpart[((size_t)p0 * I_COLS + it) * 64 + lane];
    ue -= a_ui * Wu[(size_t)lane * I_COLS + it];
    ie -= a_ui * Wi[(size_t)lane * U_ROWS + u];

    // layer 1: 128 -> 64, LN, ReLU
    float h = b1[lane];
    for (int c = 0; c < 64; ++c) h += __shfl(ue, c) * Wt1[c * 64 + lane];
    for (int c = 0; c < 64; ++c) h += __shfl(ie, c) * Wt1[(64 + c) * 64 + lane];
    {
        float m = redsum64(h) * (1.0f / 64.0f);
        float d = h - m;
        float v = redsum64(d * d) * (1.0f / 64.0f);
        h = d * rsqrtf(v + 1e-5f) * g1[lane] + be1[lane];
        h = fmaxf(h, 0.0f);
    }
    // layer 2: 64 -> 32 (upper 32 lanes mirror lower), LN, ReLU
    const int l2 = lane & 31;
    float h2 = b2[l2];
    for (int c = 0; c < 64; ++c) h2 += __shfl(h, c) * Wt2[c * 32 + l2];
    {
        float m = redsum32(h2) * (1.0f / 32.0f);
        float d = h2 - m;
        float v = redsum32(d * d) * (1.0f / 32.0f);
        h2 = d * rsqrtf(v + 1e-5f) * g2[l2] + be2[l2];
        h2 = fmaxf(h2, 0.0f);
    }
    // layer 3: 32 -> 16, LN, ReLU
    const int l3 = lane & 15;
    float h3 = b3[l3];
    for (int c = 0; c < 32; ++c) h3 += __shfl(h2, c) * Wt3[c * 16 + l3];
    {
        float m = redsum16(h3) * (1.0f / 16.0f);
        float d = h3 - m;
        float v = redsum16(d * d) * (1.0f / 16.0f);
        h3 = d * rsqrtf(v + 1e-5f) * g3[l3] + be3[l3];
        h3 = fmaxf(h3, 0.0f);
    }
    // final: dot(h3, Wp) + bp
    float tt = h3 * Wp[l3];
    tt = redsum16(tt);
    if (lane == 0) out[r] = tt + bp[0];
}

extern "C" void kernel_launch(void* const* d_in, const int* in_sizes, int n_in,
                              void* d_out, int out_size, void* d_ws, size_t ws_size,
                              hipStream_t stream)
{
    const float* A    = (const float*)d_in[0];
    const int*   uidx = (const int*)d_in[1];
    const int*   iidx = (const int*)d_in[2];
    const float* W_u  = (const float*)d_in[3];
    const float* W_i  = (const float*)d_in[4];
    const float* W1   = (const float*)d_in[5];
    const float* b1   = (const float*)d_in[6];
    const float* g1   = (const float*)d_in[7];
    const float* be1  = (const float*)d_in[8];
    const float* W2   = (const float*)d_in[9];
    const float* b2   = (const float*)d_in[10];
    const float* g2   = (const float*)d_in[11];
    const float* be2  = (const float*)d_in[12];
    const float* W3   = (const float*)d_in[13];
    const float* b3   = (const float*)d_in[14];
    const float* g3   = (const float*)d_in[15];
    const float* be3  = (const float*)d_in[16];
    const float* Wp   = (const float*)d_in[17];
    const float* bp   = (const float*)d_in[18];
    float* out = (float*)d_out;

    // workspace carving (all offsets 16B-aligned)
    unsigned short* Wtu_p = (unsigned short*)d_ws;        // SU*2048 bf16
    unsigned short* Wti_p = Wtu_p + (size_t)SU * 2048;    // SC*2048 bf16
    float* Wt1 = (float*)(Wti_p + (size_t)SC * 2048);     // 128*64
    float* Wt2 = Wt1 + 128 * 64;                          // 64*32
    float* Wt3 = Wt2 + 64 * 32;                           // 32*16
    float* Upart = Wt3 + 32 * 16;

    size_t fixed_b = (size_t)(SU + SC) * 2048 * 2 + (size_t)(128 * 64 + 64 * 32 + 32 * 16) * 4;
    int NP = 8, NC = 8;
    while (NP > 1 &&
           fixed_b + (size_t)NP * B_N * 64 * 4 + (size_t)NC * I_COLS * 64 * 4 > ws_size) {
        NP >>= 1; NC >>= 1;
    }
    float* Cpart = Upart + (size_t)NP * B_N * 64;

    int spu = (SU + NP - 1) / NP;
    int spc = (SC + NC - 1) / NC;

    hipLaunchKernelGGL(k_pack_w, dim3((SU * 2048 + 255) / 256), dim3(256), 0, stream,
                       W_u, Wtu_p, I_COLS, SU);
    hipLaunchKernelGGL(k_pack_w, dim3((SC * 2048 + 255) / 256), dim3(256), 0, stream,
                       W_i, Wti_p, U_ROWS, SC);
    hipLaunchKernelGGL(k_tr, dim3(32), dim3(256), 0, stream, W1, Wt1, 64, 128);
    hipLaunchKernelGGL(k_tr, dim3(8),  dim3(256), 0, stream, W2, Wt2, 32, 64);
    hipLaunchKernelGGL(k_tr, dim3(2),  dim3(256), 0, stream, W3, Wt3, 16, 32);

    hipLaunchKernelGGL(k_gemm_u, dim3(64 * NP), dim3(256), 0, stream,
                       A, uidx, Wtu_p, Upart, spu);
    hipLaunchKernelGGL(k_gemm_c, dim3(157 * NC), dim3(256), 0, stream,
                       A, Wti_p, Cpart, 157, spc);

    hipLaunchKernelGGL(k_epi, dim3(B_N / 4), dim3(256), 0, stream,
                       A, uidx, iidx, Upart, Cpart, NP, NC,
                       W_u, W_i, Wt1, b1, g1, be1, Wt2, b2, g2, be2,
                       Wt3, b3, g3, be3, Wp, bp, out);
}

// Round 2
// 250.377 us; speedup vs baseline: 1.2061x; 1.2061x over previous
//
#include <hip/hip_runtime.h>

#define U_ROWS 20000
#define I_COLS 10000
#define LDI    10001
#define B_N    4096
#define SU     313   // ceil(10000/32) K-steps for u-gemm
#define SC     625   // 20000/32 K-steps for c-gemm

typedef __attribute__((ext_vector_type(8))) __bf16 bf16x8;
typedef __attribute__((ext_vector_type(4))) float f32x4;

__device__ __forceinline__ unsigned short f2bf(float f) {
    unsigned int u = __float_as_uint(f);
    return (unsigned short)((u + 0x7FFFu + ((u >> 16) & 1u)) >> 16);  // RTN-even
}

// Fused prep: pack W_u and W_i into MFMA B-fragment order (bf16), transpose MLP weights.
// Pack layout: out[((s*4+nb)*64 + l)*8 + j] = bf16(W[nb*16+(l&15)][s*32+(l>>4)*8+j])
__global__ __launch_bounds__(256) void k_prep(
    const float* __restrict__ Wu, const float* __restrict__ Wi,
    unsigned short* __restrict__ Pu, unsigned short* __restrict__ Pi,
    const float* __restrict__ W1, const float* __restrict__ W2, const float* __restrict__ W3,
    float* __restrict__ Wt1, float* __restrict__ Wt2, float* __restrict__ Wt3)
{
    const int NU = SU * 2048, NC2 = SC * 2048;
    int idx = blockIdx.x * 256 + threadIdx.x;
    if (idx < NU + NC2) {
        const float* W = (idx < NU) ? Wu : Wi;
        unsigned short* out = (idx < NU) ? Pu : Pi;
        int n_k = (idx < NU) ? I_COLS : U_ROWS;
        int li = (idx < NU) ? idx : idx - NU;
        int j  = li & 7;
        int l  = (li >> 3) & 63;
        int nb = (li >> 9) & 3;
        int s  = li >> 11;
        int n  = nb * 16 + (l & 15);
        int k  = s * 32 + ((l >> 4) << 3) + j;
        float v = (k < n_k) ? W[(size_t)n * n_k + k] : 0.0f;
        out[li] = f2bf(v);
        return;
    }
    int r2 = idx - (NU + NC2);
    if (r2 < 64 * 128) { int r = r2 / 128, c = r2 % 128; Wt1[c * 64 + r] = W1[r2]; return; }
    r2 -= 64 * 128;
    if (r2 < 32 * 64)  { int r = r2 / 64,  c = r2 % 64;  Wt2[c * 32 + r] = W2[r2]; return; }
    r2 -= 32 * 64;
    if (r2 < 16 * 32)  { int r = r2 / 32,  c = r2 % 32;  Wt3[c * 16 + r] = W3[r2]; return; }
}

// Fused GEMM kernel, 2-phase reg-staged pipeline.
//  blocks [0, 157*NC):  Cpart[p][i][n] = sum_{u in range} A[u,i] * W_i[n,u]
//  blocks [157*NC, +64*NP): Upart[p][r][n] = sum_{i in range} A[u_r,i] * W_u[n,i]
__global__ __launch_bounds__(256) void k_gemm(
    const float* __restrict__ A, const int* __restrict__ uidx,
    const unsigned short* __restrict__ Bpu, const unsigned short* __restrict__ Bpc,
    float* __restrict__ Upart, float* __restrict__ Cpart,
    int spu, int spc, int NC)
{
    __shared__ float At[2048];
    const int t = threadIdx.x, lane = t & 63, w = t >> 6;
    const int rl = lane & 15, g = lane >> 4;
    const int CB = 157 * NC;

    f32x4 acc[4];
#pragma unroll
    for (int nb = 0; nb < 4; ++nb) acc[nb] = (f32x4)(0.0f);

    if ((int)blockIdx.x < CB) {
        // ---------------- c-gemm ----------------
        const int mb = blockIdx.x % 157, p = blockIdx.x / 157;
        const int i0 = mb * 64;
        const int s0 = p * spc;
        const int s1 = (SC < s0 + spc) ? SC : (s0 + spc);

#define CLOAD(dst, S) do { \
        int u0_ = (S) * 32; \
        _Pragma("unroll") \
        for (int q = 0; q < 8; ++q) { \
            int ul_ = q * 4 + w; \
            int col_ = i0 + ((lane + ul_) & 63); \
            dst[q] = (col_ < I_COLS) ? A[(size_t)(u0_ + ul_) * LDI + col_] : 0.0f; \
        } } while (0)

        float sv[8];
        CLOAD(sv, s0);
        for (int s = s0; s < s1; ++s) {
            __syncthreads();               // prev compute's LDS reads done
            float sv2[8];
            if (s + 1 < s1) { CLOAD(sv2, s + 1); }
            else {
#pragma unroll
                for (int q = 0; q < 8; ++q) sv2[q] = 0.0f;
            }
#pragma unroll
            for (int q = 0; q < 8; ++q) At[(q * 4 + w) * 64 + lane] = sv[q];

            bf16x8 bv[4];
#pragma unroll
            for (int nb = 0; nb < 4; ++nb)
                bv[nb] = *(const bf16x8*)(Bpc + ((size_t)(s * 4 + nb) * 64 + lane) * 8);
            __syncthreads();

            const int i_loc = w * 16 + rl;
            unsigned int au[8];
#pragma unroll
            for (int j = 0; j < 8; ++j) {
                int ul = g * 8 + j;
                au[j] = __float_as_uint(At[ul * 64 + ((i_loc - ul) & 63)]);
            }
            union { int i[4]; bf16x8 v; } af;
#pragma unroll
            for (int q = 0; q < 4; ++q)
                af.i[q] = __builtin_amdgcn_perm(au[2 * q + 1], au[2 * q], 0x07060302);
#pragma unroll
            for (int nb = 0; nb < 4; ++nb)
                acc[nb] = __builtin_amdgcn_mfma_f32_16x16x32_bf16(af.v, bv[nb], acc[nb], 0, 0, 0);
#pragma unroll
            for (int q = 0; q < 8; ++q) sv[q] = sv2[q];
        }

        float* outp = Cpart + (size_t)p * I_COLS * 64;
#pragma unroll
        for (int nb = 0; nb < 4; ++nb)
#pragma unroll
            for (int reg = 0; reg < 4; ++reg) {
                int i = i0 + w * 16 + g * 4 + reg;
                if (i < I_COLS) outp[(size_t)i * 64 + nb * 16 + rl] = acc[nb][reg];
            }
    } else {
        // ---------------- u-gemm ----------------
        const int bid = blockIdx.x - CB;
        const int mb = bid & 63, p = bid >> 6;
        const int r0 = mb * 64;
        const int s0 = p * spu;
        const int s1 = (SU < s0 + spu) ? SU : (s0 + spu);

        int urow[8];
#pragma unroll
        for (int q = 0; q < 8; ++q) urow[q] = uidx[r0 + q * 8 + (t >> 5)];

#define ULOAD(dst, S) do { \
        int k0_ = (S) * 32; \
        _Pragma("unroll") \
        for (int q = 0; q < 8; ++q) { \
            int row_ = q * 8 + (t >> 5); \
            int col_ = k0_ + (((t & 31) + row_) & 31); \
            dst[q] = (col_ < I_COLS) ? A[(size_t)urow[q] * LDI + col_] : 0.0f; \
        } } while (0)

        float sv[8];
        ULOAD(sv, s0);
        for (int s = s0; s < s1; ++s) {
            __syncthreads();
            float sv2[8];
            if (s + 1 < s1) { ULOAD(sv2, s + 1); }
            else {
#pragma unroll
                for (int q = 0; q < 8; ++q) sv2[q] = 0.0f;
            }
#pragma unroll
            for (int q = 0; q < 8; ++q) {
                int row = q * 8 + (t >> 5);
                At[row * 32 + (t & 31)] = sv[q];
            }
            bf16x8 bv[4];
#pragma unroll
            for (int nb = 0; nb < 4; ++nb)
                bv[nb] = *(const bf16x8*)(Bpu + ((size_t)(s * 4 + nb) * 64 + lane) * 8);
            __syncthreads();

            const int r_loc = w * 16 + rl;
            unsigned int au[8];
#pragma unroll
            for (int j = 0; j < 8; ++j) {
                int c = g * 8 + j;
                au[j] = __float_as_uint(At[r_loc * 32 + ((c - r_loc) & 31)]);
            }
            union { int i[4]; bf16x8 v; } af;
#pragma unroll
            for (int q = 0; q < 4; ++q)
                af.i[q] = __builtin_amdgcn_perm(au[2 * q + 1], au[2 * q], 0x07060302);
#pragma unroll
            for (int nb = 0; nb < 4; ++nb)
                acc[nb] = __builtin_amdgcn_mfma_f32_16x16x32_bf16(af.v, bv[nb], acc[nb], 0, 0, 0);
#pragma unroll
            for (int q = 0; q < 8; ++q) sv[q] = sv2[q];
        }

        float* outp = Upart + (size_t)p * B_N * 64;
#pragma unroll
        for (int nb = 0; nb < 4; ++nb)
#pragma unroll
            for (int reg = 0; reg < 4; ++reg) {
                int r = r0 + w * 16 + g * 4 + reg;
                outp[(size_t)r * 64 + nb * 16 + rl] = acc[nb][reg];
            }
    }
}

__device__ __forceinline__ float redsum64(float x) {
    x += __shfl_xor(x, 1);  x += __shfl_xor(x, 2);  x += __shfl_xor(x, 4);
    x += __shfl_xor(x, 8);  x += __shfl_xor(x, 16); x += __shfl_xor(x, 32);
    return x;
}
__device__ __forceinline__ float redsum32(float x) {
    x += __shfl_xor(x, 1); x += __shfl_xor(x, 2); x += __shfl_xor(x, 4);
    x += __shfl_xor(x, 8); x += __shfl_xor(x, 16);
    return x;
}
__device__ __forceinline__ float redsum16(float x) {
    x += __shfl_xor(x, 1); x += __shfl_xor(x, 2); x += __shfl_xor(x, 4);
    x += __shfl_xor(x, 8);
    return x;
}

// one wave per batch row: reduce partials, mask corrections, full MLP
__global__ __launch_bounds__(256) void k_epi(
    const float* __restrict__ A, const int* __restrict__ uidx, const int* __restrict__ iidx,
    const float* __restrict__ Upart, const float* __restrict__ Cpart, int NP, int NC,
    const float* __restrict__ Wu, const float* __restrict__ Wi,
    const float* __restrict__ Wt1, const float* __restrict__ b1, const float* __restrict__ g1, const float* __restrict__ be1,
    const float* __restrict__ Wt2, const float* __restrict__ b2, const float* __restrict__ g2, const float* __restrict__ be2,
    const float* __restrict__ Wt3, const float* __restrict__ b3, const float* __restrict__ g3, const float* __restrict__ be3,
    const float* __restrict__ Wp, const float* __restrict__ bp,
    float* __restrict__ out)
{
    const int t = threadIdx.x, lane = t & 63, w = t >> 6;
    const int r = blockIdx.x * 4 + w;
    const int u = uidx[r], it = iidx[r];
    const float a_ui = A[(size_t)u * LDI + it];

    float ue = 0.f, ie = 0.f;
    for (int p0 = 0; p0 < NP; ++p0) ue += Upart[((size_t)p0 * B_N + r) * 64 + lane];
    for (int p0 = 0; p0 < NC; ++p0) ie += Cpart[((size_t)p0 * I_COLS + it) * 64 + lane];
    ue -= a_ui * Wu[(size_t)lane * I_COLS + it];
    ie -= a_ui * Wi[(size_t)lane * U_ROWS + u];

    // layer 1: 128 -> 64, LN, ReLU
    float h = b1[lane];
    for (int c = 0; c < 64; ++c) h += __shfl(ue, c) * Wt1[c * 64 + lane];
    for (int c = 0; c < 64; ++c) h += __shfl(ie, c) * Wt1[(64 + c) * 64 + lane];
    {
        float m = redsum64(h) * (1.0f / 64.0f);
        float d = h - m;
        float v = redsum64(d * d) * (1.0f / 64.0f);
        h = d * rsqrtf(v + 1e-5f) * g1[lane] + be1[lane];
        h = fmaxf(h, 0.0f);
    }
    // layer 2: 64 -> 32
    const int l2 = lane & 31;
    float h2 = b2[l2];
    for (int c = 0; c < 64; ++c) h2 += __shfl(h, c) * Wt2[c * 32 + l2];
    {
        float m = redsum32(h2) * (1.0f / 32.0f);
        float d = h2 - m;
        float v = redsum32(d * d) * (1.0f / 32.0f);
        h2 = d * rsqrtf(v + 1e-5f) * g2[l2] + be2[l2];
        h2 = fmaxf(h2, 0.0f);
    }
    // layer 3: 32 -> 16
    const int l3 = lane & 15;
    float h3 = b3[l3];
    for (int c = 0; c < 32; ++c) h3 += __shfl(h2, c) * Wt3[c * 16 + l3];
    {
        float m = redsum16(h3) * (1.0f / 16.0f);
        float d = h3 - m;
        float v = redsum16(d * d) * (1.0f / 16.0f);
        h3 = d * rsqrtf(v + 1e-5f) * g3[l3] + be3[l3];
        h3 = fmaxf(h3, 0.0f);
    }
    float tt = h3 * Wp[l3];
    tt = redsum16(tt);
    if (lane == 0) out[r] = tt + bp[0];
}

extern "C" void kernel_launch(void* const* d_in, const int* in_sizes, int n_in,
                              void* d_out, int out_size, void* d_ws, size_t ws_size,
                              hipStream_t stream)
{
    const float* A    = (const float*)d_in[0];
    const int*   uidx = (const int*)d_in[1];
    const int*   iidx = (const int*)d_in[2];
    const float* W_u  = (const float*)d_in[3];
    const float* W_i  = (const float*)d_in[4];
    const float* W1   = (const float*)d_in[5];
    const float* b1   = (const float*)d_in[6];
    const float* g1   = (const float*)d_in[7];
    const float* be1  = (const float*)d_in[8];
    const float* W2   = (const float*)d_in[9];
    const float* b2   = (const float*)d_in[10];
    const float* g2   = (const float*)d_in[11];
    const float* be2  = (const float*)d_in[12];
    const float* W3   = (const float*)d_in[13];
    const float* b3   = (const float*)d_in[14];
    const float* g3   = (const float*)d_in[15];
    const float* be3  = (const float*)d_in[16];
    const float* Wp   = (const float*)d_in[17];
    const float* bp   = (const float*)d_in[18];
    float* out = (float*)d_out;

    unsigned short* Wtu_p = (unsigned short*)d_ws;        // SU*2048 bf16
    unsigned short* Wti_p = Wtu_p + (size_t)SU * 2048;    // SC*2048 bf16
    float* Wt1 = (float*)(Wti_p + (size_t)SC * 2048);     // 128*64
    float* Wt2 = Wt1 + 128 * 64;                          // 64*32
    float* Wt3 = Wt2 + 64 * 32;                           // 32*16
    float* Upart = Wt3 + 32 * 16;

    size_t fixed_b = (size_t)(SU + SC) * 2048 * 2 + (size_t)(128 * 64 + 64 * 32 + 32 * 16) * 4;
    int NP = 8, NC = 8;
    while (NP > 1 &&
           fixed_b + (size_t)NP * B_N * 64 * 4 + (size_t)NC * I_COLS * 64 * 4 > ws_size) {
        NP >>= 1; NC >>= 1;
    }
    float* Cpart = Upart + (size_t)NP * B_N * 64;

    int spu = (SU + NP - 1) / NP;
    int spc = (SC + NC - 1) / NC;

    int prep_tot = (SU + SC) * 2048 + 64 * 128 + 32 * 64 + 16 * 32;
    hipLaunchKernelGGL(k_prep, dim3((prep_tot + 255) / 256), dim3(256), 0, stream,
                       W_u, W_i, Wtu_p, Wti_p, W1, W2, W3, Wt1, Wt2, Wt3);

    hipLaunchKernelGGL(k_gemm, dim3(157 * NC + 64 * NP), dim3(256), 0, stream,
                       A, uidx, Wtu_p, Wti_p, Upart, Cpart, spu, spc, NC);

    hipLaunchKernelGGL(k_epi, dim3(B_N / 4), dim3(256), 0, stream,
                       A, uidx, iidx, Upart, Cpart, NP, NC,
                       W_u, W_i, Wt1, b1, g1, be1, Wt2, b2, g2, be2,
                       Wt3, b3, g3, be3, Wp, bp, out);
}